// Round 1
// baseline (111.205 us; speedup 1.0000x reference)
//
#include <hip/hip_runtime.h>
#include <math.h>

#define B_TOT 2048
#define T_N 6
#define V_N 100
#define P_N 20

// One block per batch element b. 128 threads (2 waves).
// Phase 1: threads 0..99 each own lane v, compute min squared distance to each
//          of the 6 trajectory points, then block-argmin over v with
//          first-index tie-break via 64-bit (sqrt_dist_bits<<32 | v) min-reduce.
// Phase 2: threads 0..5 each own one t: nearest point on chosen lane, yaws,
//          wrap chain, masks. Thread 0 atomically accumulates the mean.
__global__ __launch_bounds__(128) void pmdl_kernel(
    const float* __restrict__ ego,    // [B, 6, 2]
    const float* __restrict__ lane,   // [B, 100, 20, 2] (raw, unscaled)
    const float* __restrict__ score,  // [B, 100, 3]
    float* __restrict__ out)          // [1]
{
    const int b   = blockIdx.x;
    const int tid = threadIdx.x;

    // ---- trajectory cumsum (every thread; 12 floats, L1-broadcast) ----
    const float* e = ego + (size_t)b * (T_N * 2);
    float px[T_N], py[T_N];
    {
        float cx = 0.f, cy = 0.f;
        #pragma unroll
        for (int t = 0; t < T_N; ++t) {
            cx += e[2 * t];
            cy += e[2 * t + 1];
            px[t] = cx; py[t] = cy;
        }
    }
    const float tdx = px[T_N - 1] - px[0];
    const float tdy = py[T_N - 1] - py[0];
    const bool static_mask = sqrtf(tdx * tdx + tdy * tdy) < 1.0f;

    __shared__ unsigned long long keys[T_N][128];

    // ---- phase 1: per-lane min distance over P, for each t ----
    unsigned long long kk[T_N];
    if (tid < V_N) {
        const int v = tid;
        float m2[T_N];
        #pragma unroll
        for (int t = 0; t < T_N; ++t) m2[t] = 3.0e38f;

        const float sc = score[((size_t)b * V_N + v) * 3];
        if (sc < 0.5f) {
            // not a lane divider -> all 20 points masked to (1e6, 1e6)
            #pragma unroll
            for (int t = 0; t < T_N; ++t) {
                float dx = px[t] - 1e6f, dy = py[t] - 1e6f;
                m2[t] = fmaf(dx, dx, dy * dy);
            }
        } else {
            const float4* lp =
                (const float4*)(lane + ((size_t)b * V_N + v) * (P_N * 2));
            #pragma unroll
            for (int j = 0; j < P_N / 2; ++j) {
                float4 q = lp[j];
                float x0 = fmaf(q.x, 30.f, -15.f);
                float y0 = fmaf(q.y, 60.f, -30.f);
                float x1 = fmaf(q.z, 30.f, -15.f);
                float y1 = fmaf(q.w, 60.f, -30.f);
                #pragma unroll
                for (int t = 0; t < T_N; ++t) {
                    float dx0 = px[t] - x0, dy0 = py[t] - y0;
                    float d0  = fmaf(dx0, dx0, dy0 * dy0);
                    float dx1 = px[t] - x1, dy1 = py[t] - y1;
                    float d1  = fmaf(dx1, dx1, dy1 * dy1);
                    m2[t] = fminf(m2[t], fminf(d0, d1));
                }
            }
        }
        // sqrt once per (v,t): min_p sqrt(d2) == sqrt(min_p d2) (monotone)
        #pragma unroll
        for (int t = 0; t < T_N; ++t)
            kk[t] = ((unsigned long long)__float_as_uint(sqrtf(m2[t])) << 32)
                    | (unsigned)v;
    } else {
        #pragma unroll
        for (int t = 0; t < T_N; ++t) kk[t] = 0xFFFFFFFFFFFFFFFFull;
    }

    #pragma unroll
    for (int t = 0; t < T_N; ++t) keys[t][tid] = kk[t];
    __syncthreads();

    // min-reduce: smallest distance, ties -> smallest v (== jnp.argmin)
    for (int s = 64; s > 0; s >>= 1) {
        if (tid < s) {
            #pragma unroll
            for (int t = 0; t < T_N; ++t) {
                unsigned long long a = keys[t][tid];
                unsigned long long c = keys[t][tid + s];
                keys[t][tid] = (c < a) ? c : a;
            }
        }
        __syncthreads();
    }

    // ---- phase 2: per-t nearest point + yaw loss ----
    __shared__ float tloss[T_N];
    if (tid < T_N) {
        const int t = tid;
        const unsigned vsel = (unsigned)(keys[t][0] & 0xFFFFFFFFu);
        const float sc = score[((size_t)b * V_N + vsel) * 3];
        const bool real = !(sc < 0.5f);  // false -> lane masked to 1e6
        const float* basep = lane + ((size_t)b * V_N + vsel) * (P_N * 2);

        // argmin over 20 points of sqrt distance (strict '<' keeps first idx)
        float best = 3.0e38f;
        int   bi   = 0;
        const float4* lp = (const float4*)basep;
        #pragma unroll
        for (int j = 0; j < P_N / 2; ++j) {
            float4 q = lp[j];
            float x0 = real ? fmaf(q.x, 30.f, -15.f) : 1e6f;
            float y0 = real ? fmaf(q.y, 60.f, -30.f) : 1e6f;
            float x1 = real ? fmaf(q.z, 30.f, -15.f) : 1e6f;
            float y1 = real ? fmaf(q.w, 60.f, -30.f) : 1e6f;
            float dx0 = x0 - px[t], dy0 = y0 - py[t];
            float d0  = sqrtf(fmaf(dx0, dx0, dy0 * dy0));
            float dx1 = x1 - px[t], dy1 = y1 - py[t];
            float d1  = sqrtf(fmaf(dx1, dx1, dy1 * dy1));
            if (d0 < best) { best = d0; bi = 2 * j; }
            if (d1 < best) { best = d1; bi = 2 * j + 1; }
        }
        const int ni = (bi == P_N - 1) ? P_N - 2 : bi + 1;

        // reload the two chosen points directly (no runtime-indexed arrays)
        const float2* lp2 = (const float2*)basep;
        float2 c2 = lp2[bi];
        float2 n2 = lp2[ni];
        float cxp = real ? fmaf(c2.x, 30.f, -15.f) : 1e6f;
        float cyp = real ? fmaf(c2.y, 60.f, -30.f) : 1e6f;
        float nxp = real ? fmaf(n2.x, 30.f, -15.f) : 1e6f;
        float nyp = real ? fmaf(n2.y, 60.f, -30.f) : 1e6f;

        // traj yaw from diff(cumsum) — recomputed from pred, not raw ego
        float yawx = (t < T_N - 1) ? (px[t + 1] - px[t])
                                   : (px[T_N - 1] - px[T_N - 2]);
        float yawy = (t < T_N - 1) ? (py[t + 1] - py[t])
                                   : (py[T_N - 1] - py[T_N - 2]);
        float tyaw = atan2f(yawy, yawx);
        float lyaw = atan2f(nyp - cyp, nxp - cxp);

        float yd = tyaw - lyaw;
        const float PIf = 3.14159274101257324f;  // (float)math.pi
        if (yd >  PIf)        yd -= PIf;
        if (yd >  0.5f * PIf) yd -= PIf;
        if (yd < -PIf)        yd += PIf;
        if (yd < -0.5f * PIf) yd += PIf;
        if (best > 2.0f)  yd = 0.f;   // dist_mask
        if (static_mask)  yd = 0.f;
        tloss[t] = fabsf(yd);
    }
    __syncthreads();

    if (tid == 0) {
        float s = 0.f;
        #pragma unroll
        for (int t = 0; t < T_N; ++t) s += tloss[t];
        atomicAdd(out, s * (1.0f / (float)(B_TOT * T_N)));
    }
}

extern "C" void kernel_launch(void* const* d_in, const int* in_sizes, int n_in,
                              void* d_out, int out_size, void* d_ws, size_t ws_size,
                              hipStream_t stream) {
    const float* ego   = (const float*)d_in[0];  // [2048,6,2]
    const float* lane  = (const float*)d_in[1];  // [2048,100,20,2]
    const float* score = (const float*)d_in[2];  // [2048,100,3]
    float* out = (float*)d_out;

    // d_out is poisoned with 0xAA before every timed launch -> zero it.
    hipMemsetAsync(out, 0, sizeof(float), stream);

    pmdl_kernel<<<B_TOT, 128, 0, stream>>>(ego, lane, score, out);
}

// Round 2
// 89.291 us; speedup vs baseline: 1.2454x; 1.2454x over previous
//
#include <hip/hip_runtime.h>
#include <math.h>

#define B_TOT 2048
#define T_N 6
#define V_N 100
#define P_N 20

// Kernel 1: one block per batch element b. 128 threads (2 waves).
// Phase 1: threads 0..99 each own lane v, compute min distance to each of the
//          6 trajectory points, then block-argmin over v with first-index
//          tie-break via 64-bit (sqrt_dist_bits<<32 | v) min-reduce.
// Phase 2: threads 0..5 each own one t: nearest point on chosen lane, yaws,
//          wrap chain, masks. Thread 0 writes the block partial to ws[b].
// NO atomics: 2048 same-address device atomicAdds serialize across the 8
// non-coherent XCDs (~50 ns each ≈ 100 µs — the R1 bottleneck).
__global__ __launch_bounds__(128) void pmdl_kernel(
    const float* __restrict__ ego,    // [B, 6, 2]
    const float* __restrict__ lane,   // [B, 100, 20, 2] (raw, unscaled)
    const float* __restrict__ score,  // [B, 100, 3]
    float* __restrict__ partial)      // [B]
{
    const int b   = blockIdx.x;
    const int tid = threadIdx.x;

    // ---- trajectory cumsum (every thread; 12 floats, L1-broadcast) ----
    const float* e = ego + (size_t)b * (T_N * 2);
    float px[T_N], py[T_N];
    {
        float cx = 0.f, cy = 0.f;
        #pragma unroll
        for (int t = 0; t < T_N; ++t) {
            cx += e[2 * t];
            cy += e[2 * t + 1];
            px[t] = cx; py[t] = cy;
        }
    }
    const float tdx = px[T_N - 1] - px[0];
    const float tdy = py[T_N - 1] - py[0];
    const bool static_mask = sqrtf(tdx * tdx + tdy * tdy) < 1.0f;

    __shared__ unsigned long long keys[T_N][128];

    // ---- phase 1: per-lane min distance over P, for each t ----
    unsigned long long kk[T_N];
    if (tid < V_N) {
        const int v = tid;
        float m2[T_N];
        #pragma unroll
        for (int t = 0; t < T_N; ++t) m2[t] = 3.0e38f;

        const float sc = score[((size_t)b * V_N + v) * 3];
        if (sc < 0.5f) {
            // not a lane divider -> all 20 points masked to (1e6, 1e6)
            #pragma unroll
            for (int t = 0; t < T_N; ++t) {
                float dx = px[t] - 1e6f, dy = py[t] - 1e6f;
                m2[t] = fmaf(dx, dx, dy * dy);
            }
        } else {
            const float4* lp =
                (const float4*)(lane + ((size_t)b * V_N + v) * (P_N * 2));
            #pragma unroll
            for (int j = 0; j < P_N / 2; ++j) {
                float4 q = lp[j];
                float x0 = fmaf(q.x, 30.f, -15.f);
                float y0 = fmaf(q.y, 60.f, -30.f);
                float x1 = fmaf(q.z, 30.f, -15.f);
                float y1 = fmaf(q.w, 60.f, -30.f);
                #pragma unroll
                for (int t = 0; t < T_N; ++t) {
                    float dx0 = px[t] - x0, dy0 = py[t] - y0;
                    float d0  = fmaf(dx0, dx0, dy0 * dy0);
                    float dx1 = px[t] - x1, dy1 = py[t] - y1;
                    float d1  = fmaf(dx1, dx1, dy1 * dy1);
                    m2[t] = fminf(m2[t], fminf(d0, d1));
                }
            }
        }
        // sqrt once per (v,t): min_p sqrtf(d2) == sqrtf(min_p d2) (monotone,
        // correctly-rounded) — and ref compares sqrt'd values for ties.
        #pragma unroll
        for (int t = 0; t < T_N; ++t)
            kk[t] = ((unsigned long long)__float_as_uint(sqrtf(m2[t])) << 32)
                    | (unsigned)v;
    } else {
        #pragma unroll
        for (int t = 0; t < T_N; ++t) kk[t] = 0xFFFFFFFFFFFFFFFFull;
    }

    #pragma unroll
    for (int t = 0; t < T_N; ++t) keys[t][tid] = kk[t];
    __syncthreads();

    // min-reduce: smallest distance, ties -> smallest v (== jnp.argmin)
    for (int s = 64; s > 0; s >>= 1) {
        if (tid < s) {
            #pragma unroll
            for (int t = 0; t < T_N; ++t) {
                unsigned long long a = keys[t][tid];
                unsigned long long c = keys[t][tid + s];
                keys[t][tid] = (c < a) ? c : a;
            }
        }
        __syncthreads();
    }

    // ---- phase 2: per-t nearest point + yaw loss ----
    __shared__ float tloss[T_N];
    if (tid < T_N) {
        const int t = tid;
        const unsigned vsel = (unsigned)(keys[t][0] & 0xFFFFFFFFu);
        const float sc = score[((size_t)b * V_N + vsel) * 3];
        const bool real = !(sc < 0.5f);  // false -> lane masked to 1e6
        const float* basep = lane + ((size_t)b * V_N + vsel) * (P_N * 2);

        // argmin over 20 points of sqrt distance (strict '<' keeps first idx)
        float best = 3.0e38f;
        int   bi   = 0;
        const float4* lp = (const float4*)basep;
        #pragma unroll
        for (int j = 0; j < P_N / 2; ++j) {
            float4 q = lp[j];
            float x0 = real ? fmaf(q.x, 30.f, -15.f) : 1e6f;
            float y0 = real ? fmaf(q.y, 60.f, -30.f) : 1e6f;
            float x1 = real ? fmaf(q.z, 30.f, -15.f) : 1e6f;
            float y1 = real ? fmaf(q.w, 60.f, -30.f) : 1e6f;
            float dx0 = x0 - px[t], dy0 = y0 - py[t];
            float d0  = sqrtf(fmaf(dx0, dx0, dy0 * dy0));
            float dx1 = x1 - px[t], dy1 = y1 - py[t];
            float d1  = sqrtf(fmaf(dx1, dx1, dy1 * dy1));
            if (d0 < best) { best = d0; bi = 2 * j; }
            if (d1 < best) { best = d1; bi = 2 * j + 1; }
        }
        const int ni = (bi == P_N - 1) ? P_N - 2 : bi + 1;

        // reload the two chosen points directly (no runtime-indexed arrays)
        const float2* lp2 = (const float2*)basep;
        float2 c2 = lp2[bi];
        float2 n2 = lp2[ni];
        float cxp = real ? fmaf(c2.x, 30.f, -15.f) : 1e6f;
        float cyp = real ? fmaf(c2.y, 60.f, -30.f) : 1e6f;
        float nxp = real ? fmaf(n2.x, 30.f, -15.f) : 1e6f;
        float nyp = real ? fmaf(n2.y, 60.f, -30.f) : 1e6f;

        // traj yaw from diff(cumsum) — recomputed from pred, not raw ego
        float yawx = (t < T_N - 1) ? (px[t + 1] - px[t])
                                   : (px[T_N - 1] - px[T_N - 2]);
        float yawy = (t < T_N - 1) ? (py[t + 1] - py[t])
                                   : (py[T_N - 1] - py[T_N - 2]);
        float tyaw = atan2f(yawy, yawx);
        float lyaw = atan2f(nyp - cyp, nxp - cxp);

        float yd = tyaw - lyaw;
        const float PIf = 3.14159274101257324f;  // (float)math.pi
        if (yd >  PIf)        yd -= PIf;
        if (yd >  0.5f * PIf) yd -= PIf;
        if (yd < -PIf)        yd += PIf;
        if (yd < -0.5f * PIf) yd += PIf;
        if (best > 2.0f)  yd = 0.f;   // dist_mask
        if (static_mask)  yd = 0.f;
        tloss[t] = fabsf(yd);
    }
    __syncthreads();

    if (tid == 0) {
        float s = 0.f;
        #pragma unroll
        for (int t = 0; t < T_N; ++t) s += tloss[t];
        partial[b] = s;   // plain coalesced store — no atomic
    }
}

// Kernel 2: single block reduces the 2048 partials and stores the mean.
__global__ __launch_bounds__(256) void pmdl_reduce(
    const float* __restrict__ partial,  // [B]
    float* __restrict__ out)            // [1]
{
    const int tid = threadIdx.x;
    float s = 0.f;
    for (int i = tid; i < B_TOT; i += 256) s += partial[i];
    // wave64 shuffle reduce
    #pragma unroll
    for (int off = 32; off > 0; off >>= 1) s += __shfl_down(s, off, 64);
    __shared__ float wsum[4];
    if ((tid & 63) == 0) wsum[tid >> 6] = s;
    __syncthreads();
    if (tid == 0) {
        float tot = wsum[0] + wsum[1] + wsum[2] + wsum[3];
        out[0] = tot * (1.0f / (float)(B_TOT * T_N));
    }
}

extern "C" void kernel_launch(void* const* d_in, const int* in_sizes, int n_in,
                              void* d_out, int out_size, void* d_ws, size_t ws_size,
                              hipStream_t stream) {
    const float* ego   = (const float*)d_in[0];  // [2048,6,2]
    const float* lane  = (const float*)d_in[1];  // [2048,100,20,2]
    const float* score = (const float*)d_in[2];  // [2048,100,3]
    float* partial = (float*)d_ws;               // 2048 floats, fully rewritten
    float* out     = (float*)d_out;

    pmdl_kernel<<<B_TOT, 128, 0, stream>>>(ego, lane, score, partial);
    pmdl_reduce<<<1, 256, 0, stream>>>(partial, out);
}

// Round 3
// 87.830 us; speedup vs baseline: 1.2661x; 1.0166x over previous
//
#include <hip/hip_runtime.h>
#include <math.h>

#define B_TOT 2048
#define T_N 6
#define V_N 100
#define P_N 20

// Kernel 1: one block (128 thr = 2 waves) per batch element b.
// Phase 1: thread v in [0,100) computes min distance from each of the 6
//          trajectory points to its lane (sc<0.5 lanes skip the 160B load —
//          halves HBM bytes). Per-wave argmin via 6x shfl_down + ballot/ffs
//          (ties -> lowest lane -> lowest v == jnp.argmin), inter-wave combine
//          through 96B of LDS. ONE barrier total (R2 had 8).
// Phase 2: lanes 0..5 of wave 0: nearest point on chosen lane, yaws, wrap
//          chain, masks; in-wave shuffle sum; lane 0 stores partial[b].
// No atomics (R1 lesson: 2048 same-address device atomics ~ 100 us).
__global__ __launch_bounds__(128) void pmdl_kernel(
    const float* __restrict__ ego,    // [B, 6, 2]
    const float* __restrict__ lane,   // [B, 100, 20, 2] (raw, unscaled)
    const float* __restrict__ score,  // [B, 100, 3]
    float* __restrict__ partial)      // [B]
{
    const int b   = blockIdx.x;
    const int tid = threadIdx.x;
    const int wv  = tid >> 6;
    const int ln  = tid & 63;

    // ---- trajectory cumsum (uniform-address scalar loads, broadcast) ----
    const float* e = ego + (size_t)b * (T_N * 2);
    float px[T_N], py[T_N];
    {
        float cx = 0.f, cy = 0.f;
        #pragma unroll
        for (int t = 0; t < T_N; ++t) {
            cx += e[2 * t];
            cy += e[2 * t + 1];
            px[t] = cx; py[t] = cy;
        }
    }
    const float tdx = px[T_N - 1] - px[0];
    const float tdy = py[T_N - 1] - py[0];
    const bool static_mask = sqrtf(tdx * tdx + tdy * tdy) < 1.0f;

    // ---- phase 1: per-lane (v==tid) min distance over P, for each t ----
    float dmin[T_N];
    #pragma unroll
    for (int t = 0; t < T_N; ++t) dmin[t] = 3.0e38f;   // tid>=100 stays +big

    if (tid < V_N) {
        float m2[T_N];
        #pragma unroll
        for (int t = 0; t < T_N; ++t) m2[t] = 3.0e38f;

        const float sc = score[((size_t)b * V_N + tid) * 3];
        if (sc < 0.5f) {
            // not a lane divider -> all 20 points masked to (1e6, 1e6)
            #pragma unroll
            for (int t = 0; t < T_N; ++t) {
                float dx = px[t] - 1e6f, dy = py[t] - 1e6f;
                m2[t] = fmaf(dx, dx, dy * dy);
            }
        } else {
            const float4* lp =
                (const float4*)(lane + ((size_t)b * V_N + tid) * (P_N * 2));
            #pragma unroll
            for (int j = 0; j < P_N / 2; ++j) {
                float4 q = lp[j];
                float x0 = fmaf(q.x, 30.f, -15.f);
                float y0 = fmaf(q.y, 60.f, -30.f);
                float x1 = fmaf(q.z, 30.f, -15.f);
                float y1 = fmaf(q.w, 60.f, -30.f);
                #pragma unroll
                for (int t = 0; t < T_N; ++t) {
                    float dx0 = px[t] - x0, dy0 = py[t] - y0;
                    float d0  = fmaf(dx0, dx0, dy0 * dy0);
                    float dx1 = px[t] - x1, dy1 = py[t] - y1;
                    float d1  = fmaf(dx1, dx1, dy1 * dy1);
                    m2[t] = fminf(m2[t], fminf(d0, d1));
                }
            }
        }
        // sqrt once per (v,t): min_p sqrtf(d2) == sqrtf(min_p d2) (monotone)
        #pragma unroll
        for (int t = 0; t < T_N; ++t) dmin[t] = sqrtf(m2[t]);
    }

    // ---- per-wave min + first-index argmin, 96B LDS handoff, 1 barrier ----
    __shared__ float smin[2][T_N];
    __shared__ int   svid[2][T_N];
    #pragma unroll
    for (int t = 0; t < T_N; ++t) {
        float m = dmin[t];
        #pragma unroll
        for (int off = 32; off > 0; off >>= 1)
            m = fminf(m, __shfl_down(m, off, 64));
        m = __shfl(m, 0, 64);                       // broadcast wave-min
        unsigned long long eq = __ballot(dmin[t] == m);
        if (ln == 0) {
            smin[wv][t] = m;
            svid[wv][t] = (wv << 6) + (__ffsll(eq) - 1);  // first lane == min v
        }
    }
    __syncthreads();

    if (wv == 0) {
        float loss = 0.f;
        if (ln < T_N) {
            const int t = ln;
            const float m0 = smin[0][t], m1 = smin[1][t];
            // tie -> wave 0 (its v in [0,64) < wave 1's v in [64,100))
            const int vsel = (m1 < m0) ? svid[1][t] : svid[0][t];

            const float sc = score[((size_t)b * V_N + vsel) * 3];
            const bool real = !(sc < 0.5f);  // false -> lane masked to 1e6
            const float* basep = lane + ((size_t)b * V_N + vsel) * (P_N * 2);

            // argmin over 20 points (strict '<' keeps first index)
            float best = 3.0e38f;
            int   bi   = 0;
            const float4* lp = (const float4*)basep;
            #pragma unroll
            for (int j = 0; j < P_N / 2; ++j) {
                float4 q = lp[j];
                float x0 = real ? fmaf(q.x, 30.f, -15.f) : 1e6f;
                float y0 = real ? fmaf(q.y, 60.f, -30.f) : 1e6f;
                float x1 = real ? fmaf(q.z, 30.f, -15.f) : 1e6f;
                float y1 = real ? fmaf(q.w, 60.f, -30.f) : 1e6f;
                float dx0 = x0 - px[t], dy0 = y0 - py[t];
                float d0  = sqrtf(fmaf(dx0, dx0, dy0 * dy0));
                float dx1 = x1 - px[t], dy1 = y1 - py[t];
                float d1  = sqrtf(fmaf(dx1, dx1, dy1 * dy1));
                if (d0 < best) { best = d0; bi = 2 * j; }
                if (d1 < best) { best = d1; bi = 2 * j + 1; }
            }
            const int ni = (bi == P_N - 1) ? P_N - 2 : bi + 1;

            // reload chosen points directly (no runtime-indexed reg arrays)
            const float2* lp2 = (const float2*)basep;
            float2 c2 = lp2[bi];
            float2 n2 = lp2[ni];
            float cxp = real ? fmaf(c2.x, 30.f, -15.f) : 1e6f;
            float cyp = real ? fmaf(c2.y, 60.f, -30.f) : 1e6f;
            float nxp = real ? fmaf(n2.x, 30.f, -15.f) : 1e6f;
            float nyp = real ? fmaf(n2.y, 60.f, -30.f) : 1e6f;

            // traj yaw from diff(cumsum) — recomputed from pred, not raw ego
            float yawx = (t < T_N - 1) ? (px[t + 1] - px[t])
                                       : (px[T_N - 1] - px[T_N - 2]);
            float yawy = (t < T_N - 1) ? (py[t + 1] - py[t])
                                       : (py[T_N - 1] - py[T_N - 2]);
            float tyaw = atan2f(yawy, yawx);
            float lyaw = atan2f(nyp - cyp, nxp - cxp);

            float yd = tyaw - lyaw;
            const float PIf = 3.14159274101257324f;  // (float)math.pi
            if (yd >  PIf)        yd -= PIf;
            if (yd >  0.5f * PIf) yd -= PIf;
            if (yd < -PIf)        yd += PIf;
            if (yd < -0.5f * PIf) yd += PIf;
            if (best > 2.0f)  yd = 0.f;   // dist_mask
            if (static_mask)  yd = 0.f;
            loss = fabsf(yd);
        }
        // in-wave sum of lanes 0..5 (others contribute 0), no barrier
        #pragma unroll
        for (int off = 32; off > 0; off >>= 1)
            loss += __shfl_down(loss, off, 64);
        if (ln == 0) partial[b] = loss;   // plain coalesced store
    }
}

// Kernel 2: single block reduces the 2048 partials and stores the mean.
__global__ __launch_bounds__(256) void pmdl_reduce(
    const float* __restrict__ partial,  // [B]
    float* __restrict__ out)            // [1]
{
    const int tid = threadIdx.x;
    float s = 0.f;
    #pragma unroll
    for (int i = 0; i < B_TOT / 256; ++i) s += partial[tid + i * 256];
    #pragma unroll
    for (int off = 32; off > 0; off >>= 1) s += __shfl_down(s, off, 64);
    __shared__ float wsum[4];
    if ((tid & 63) == 0) wsum[tid >> 6] = s;
    __syncthreads();
    if (tid == 0) {
        float tot = wsum[0] + wsum[1] + wsum[2] + wsum[3];
        out[0] = tot * (1.0f / (float)(B_TOT * T_N));
    }
}

extern "C" void kernel_launch(void* const* d_in, const int* in_sizes, int n_in,
                              void* d_out, int out_size, void* d_ws, size_t ws_size,
                              hipStream_t stream) {
    const float* ego   = (const float*)d_in[0];  // [2048,6,2]
    const float* lane  = (const float*)d_in[1];  // [2048,100,20,2]
    const float* score = (const float*)d_in[2];  // [2048,100,3]
    float* partialbuf = (float*)d_ws;            // 2048 floats, fully rewritten
    float* out        = (float*)d_out;

    pmdl_kernel<<<B_TOT, 128, 0, stream>>>(ego, lane, score, partialbuf);
    pmdl_reduce<<<1, 256, 0, stream>>>(partialbuf, out);
}